// Round 13
// baseline (222.637 us; speedup 1.0000x reference)
//
#include <hip/hip_runtime.h>
#include <cstdint>
#include <cstddef>

#define B_ 2
#define S_ 4096
#define D_ 1024
#define H_ 16
#define HD_ 64
#define NB_ 64
#define W_ 8
#define M_ (B_*S_)   // 8192

// 0.125 (1/sqrt(HD)) * log2(e), folded into Q so attention softmax = exp2(S)
#define QSCALE 0.18033688011112042f
#define LOG2_10000_OVER_32 0.41524101186092034f

typedef __bf16 bf16_t;
typedef __bf16 bf16x8 __attribute__((ext_vector_type(8)));
typedef float f32x4 __attribute__((ext_vector_type(4)));

#define GLOAD_LDS16(gp, lp) \
  __builtin_amdgcn_global_load_lds((__attribute__((address_space(1))) void*)(gp), \
                                   (__attribute__((address_space(3))) void*)(lp), 16, 0, 0)
#define WAITV(n) asm volatile("s_waitcnt vmcnt(" #n ")" ::: "memory")
#define BAR() do { __builtin_amdgcn_s_barrier(); asm volatile("" ::: "memory"); } while (0)

// ---------------- fused prep: fp32->bf16 cast of hidden states + weight transpose ------
__global__ __launch_bounds__(256) void prep_kernel(const float* __restrict__ hs,
                                                   bf16_t* __restrict__ hsb,
                                                   const float* __restrict__ w0,
                                                   const float* __restrict__ w1,
                                                   const float* __restrict__ w2,
                                                   const float* __restrict__ w3,
                                                   bf16_t* __restrict__ wT) {
  __shared__ float tile[32][33];
  const int bid = blockIdx.x;
  if (bid < (M_ * D_ / 4) / 256) {
    int i = bid * 256 + threadIdx.x;
    float4 v = ((const float4*)hs)[i];
    union { bf16_t b[4]; uint2 u; } cv;
    cv.b[0] = (bf16_t)v.x; cv.b[1] = (bf16_t)v.y; cv.b[2] = (bf16_t)v.z; cv.b[3] = (bf16_t)v.w;
    ((uint2*)hsb)[i] = cv.u;
  } else {
    const int b2 = bid - (M_ * D_ / 4) / 256;
    const int z = b2 >> 10;                 // 1024 tiles per matrix (32x32 grid)
    const int rem = b2 & 1023;
    const int bx = rem & 31, by = rem >> 5;
    const float* w = (z == 0) ? w0 : (z == 1) ? w1 : (z == 2) ? w2 : w3;
    bf16_t* wt = wT + (size_t)z * D_ * D_;
    const int tx = threadIdx.x & 31, ty = threadIdx.x >> 5;
    const int x = bx * 32 + tx;
    const int y0 = by * 32;
    for (int i = ty; i < 32; i += 8)
      tile[i][tx] = w[(size_t)(y0 + i) * D_ + x];
    __syncthreads();
    const int x2 = by * 32 + tx;   // k
    const int y2 = bx * 32;        // n base
    for (int i = ty; i < 32; i += 8)
      wt[(size_t)(y2 + i) * D_ + x2] = (bf16_t)tile[tx][i];
  }
}

// ---------------- GEMM: 128x128 tile, 4 waves, BK=32, 3-buf counted-vmcnt, 3 blocks/CU --
// Round-13: same proven depth-2 counted schedule (R7/R10), smaller block so THREE
// barrier-groups co-reside per CU (buffer (128+128)x32x2B = 16 KB; 3 bufs = 48 KB;
// 12 waves/CU). Per-wave tile still 64x64 (acc[4][4], 16 MFMA : 8 ds_read per phase,
// VGPR ~64 — identical per-wave code to R7). Grids quantize exactly: QKV 1536 = 2
// cohort rounds; proj 512 = one fully-co-resident round.
// A/B ledger: depth-1@3-blocks = worse (R8); 1-block lockstep = worse (R2-R6);
// acc[8][4] reg-cap spill (R5); attn big-tile at lower occupancy = worse (R11).
// NBC = column blocks of 128: 24 = merged QKV (fused RoPE/V epilogues), 8 = proj.
template<int NBC>
__global__ __launch_bounds__(256, 4) void gemm_bk(const bf16_t* __restrict__ A,
                                                  const bf16_t* __restrict__ Bt,
                                                  void* __restrict__ Cbase,
                                                  bf16_t* __restrict__ vt_out,
                                                  const int* __restrict__ pos_ids) {
  constexpr int BUFEL = 8192;             // A 128x32 | B 128x32 (elements)
  const int bid = blockIdx.x;
  const int sid = (bid & 7) * (NBC * 8) + (bid >> 3);  // XCD swizzle; nwg%8==0, bijective
  const int mb = sid / NBC, nb = sid % NBC;            // 64 x NBC blocks
  const int mbase = mb * 128, nbase = nb * 128;
  const int tid = threadIdx.x;
  const int wid = tid >> 6, lane = tid & 63;
  const int quad = lane >> 4, l16 = lane & 15;
  const int wr = wid >> 1, wc = wid & 1;               // 2 x 2 wave grid; per-wave 64 x 64

  __shared__ bf16_t lds[3 * BUFEL];   // 48 KiB

  // staging: wave wid covers A rows [wid*32,+32) and B rows [wid*32,+32), 2 gloads each
  // (16 rows x 32 cols per gload). Linear LDS dest. Source chunk pre-swizzled:
  // s(row) = (row>>1)&3; row = wid*32 + (lane>>2)  (+16 for 2nd gload, 16>>1 == 0 mod 4)
  // => s(row) = (lane>>3)&3 for both.
  const int srow = wid * 32 + (lane >> 2);
  const int schunk = (lane & 3) ^ ((lane >> 3) & 3);
  const bf16_t* gAb = A  + (size_t)(mbase + srow) * D_ + schunk * 8;
  const bf16_t* gBb = Bt + (size_t)(nbase + srow) * D_ + schunk * 8;
  // read-side swizzled chunk offset (elements): chunk = quad ^ ((l16>>1)&3)
  const int quadx = (quad ^ ((l16 >> 1) & 3)) * 8;

  // buf layout (elements): [0,4096) = A (128x32), [4096,8192) = B (128x32)
#define STAGE(kt) do { \
    bf16_t* pa_ = lds + ((kt) % 3) * BUFEL + wid * 1024; \
    bf16_t* pb_ = lds + ((kt) % 3) * BUFEL + 4096 + wid * 1024; \
    GLOAD_LDS16(gAb + (kt) * 32, pa_); \
    GLOAD_LDS16(gAb + (size_t)16 * D_ + (kt) * 32, pa_ + 512); \
    GLOAD_LDS16(gBb + (kt) * 32, pb_); \
    GLOAD_LDS16(gBb + (size_t)16 * D_ + (kt) * 32, pb_ + 512); } while (0)

  f32x4 acc[4][4];
#pragma unroll
  for (int m = 0; m < 4; ++m)
#pragma unroll
    for (int n = 0; n < 4; ++n) acc[m][n] = (f32x4){0.f, 0.f, 0.f, 0.f};

  // Phase(kt): {8 ds_read | issue stage | 16 MFMA prio1 | counted wait | BAR}.
#define PHASE(kt, STG, WT) do { \
    const bf16_t* Ab_ = lds + ((kt) % 3) * BUFEL; \
    const bf16_t* Bb_ = Ab_ + 4096; \
    bf16x8 af_[4], bf_[4]; \
    _Pragma("unroll") \
    for (int m = 0; m < 4; ++m) \
      af_[m] = *(const bf16x8*)&Ab_[(wr * 64 + m * 16 + l16) * 32 + quadx]; \
    _Pragma("unroll") \
    for (int n = 0; n < 4; ++n) \
      bf_[n] = *(const bf16x8*)&Bb_[(wc * 64 + n * 16 + l16) * 32 + quadx]; \
    STG; \
    __builtin_amdgcn_s_setprio(1); \
    _Pragma("unroll") \
    for (int m = 0; m < 4; ++m) \
      _Pragma("unroll") \
      for (int n = 0; n < 4; ++n) \
        acc[m][n] = __builtin_amdgcn_mfma_f32_16x16x32_bf16(af_[m], bf_[n], acc[m][n], 0, 0, 0); \
    __builtin_amdgcn_s_setprio(0); \
    WT; \
    BAR(); \
  } while (0)

  // depth-2 counted pipeline: during phase kt issue S(kt+2) (4 loads, 8 outstanding);
  // WAITV(4) completes S(kt+1), leaves S(kt+2) in flight. Tail drains 4 -> 0.
  STAGE(0); STAGE(1);
  WAITV(4);
  BAR();
#pragma unroll 3
  for (int kt = 0; kt < 30; ++kt)
    PHASE(kt, STAGE(kt + 2), WAITV(4));
  PHASE(30, (void)0, WAITV(0));   // drains S(31)
  PHASE(31, (void)0, (void)0);

  // ---------------- epilogue ----------------
  // C/D fragment map: row = mbase + wr*64 + m*16 + quad*4 + r, col = nbase + wc*64 + n*16 + l16.
  if constexpr (NBC == 24) {
    const int zsl = nb >> 3;           // 0=Q, 1=K, 2=V (8 col-blocks of 128 per slice)
    if (zsl < 2) {
      bf16_t* Cp = (bf16_t*)Cbase + (size_t)zsl * M_ * D_;
      const float qsc = (zsl == 0) ? QSCALE : 1.0f;
      float invf[2];
#pragma unroll
      for (int ni = 0; ni < 2; ++ni)
        invf[ni] = __builtin_exp2f(-(float)(ni * 16 + l16) * LOG2_10000_OVER_32);
      const int colb = (nb & 7) * 128 + wc * 64;   // within-slice col base; wave = one head
#pragma unroll
      for (int m = 0; m < 4; ++m) {
#pragma unroll
        for (int r = 0; r < 4; ++r) {
          int row = mbase + wr * 64 + m * 16 + quad * 4 + r;
          float fpos = (float)pos_ids[row];
#pragma unroll
          for (int ni = 0; ni < 2; ++ni) {
            float sn, cs;
            __sincosf(fpos * invf[ni], &sn, &cs);
            float x1 = acc[m][ni][r], x2 = acc[m][ni + 2][r];
            int col = colb + ni * 16 + l16;
            Cp[(size_t)row * D_ + col]      = (bf16_t)((x1 * cs - x2 * sn) * qsc);
            Cp[(size_t)row * D_ + col + 32] = (bf16_t)((x2 * cs + x1 * sn) * qsc);
          }
        }
      }
    } else {
      // V: transposed + pi-permuted, pi(j) = (j%16)*4 + j/16 within each 64-row seq block.
      const int h = (nb & 7) * 2 + wc;        // head = within-slice col base / 64
      const int g = mb * 2 + wr;              // global 64-row block in M
      const int bb = g >> 6, sblk = g & 63;   // batch, seq-block
      size_t vbase = (size_t)(bb * H_ + h) * HD_ * S_;
#pragma unroll
      for (int n = 0; n < 4; ++n) {
        int d = n * 16 + l16;
        union { bf16_t bv[16]; uint4 u[2]; } pk;
#pragma unroll
        for (int r = 0; r < 4; ++r)
#pragma unroll
          for (int mi = 0; mi < 4; ++mi)
            pk.bv[r * 4 + mi] = (bf16_t)acc[mi][n][r];
        size_t addr = vbase + (size_t)d * S_ + (size_t)sblk * 64 + quad * 16;
        *(uint4*)&vt_out[addr]     = pk.u[0];
        *(uint4*)&vt_out[addr + 8] = pk.u[1];
      }
    }
  } else {
    // plain fp32 output (out projection)
    float* Cp = (float*)Cbase;
#pragma unroll
    for (int m = 0; m < 4; ++m)
#pragma unroll
      for (int n = 0; n < 4; ++n)
#pragma unroll
        for (int r = 0; r < 4; ++r) {
          int row = mbase + wr * 64 + m * 16 + quad * 4 + r;
          int col = nbase + wc * 64 + n * 16 + l16;
          Cp[(size_t)row * D_ + col] = acc[m][n][r];
        }
  }
#undef PHASE
#undef STAGE
}

// ---------------- block-sparse flash attention: 2 q-blocks, 8 waves ----------------
// R10 structure + R12 XCD-local m-swizzle (both proven): waves 0-3 own q-block n0,
// waves 4-7 own n1; K/V staged once, counted WAITV(2) pipeline; XOR chunk swizzle
// both-sides (conflict-free); m = 4*(x&7)+(x>>3) keeps overlapping K/V windows on
// one XCD's L2. LDS 50.4 KB -> 3 blocks/CU.
__global__ __launch_bounds__(512) void attn_kernel(const bf16_t* __restrict__ q,
                                                   const bf16_t* __restrict__ k,
                                                   const bf16_t* __restrict__ vt,
                                                   bf16_t* __restrict__ o) {
  const int m = 4 * (blockIdx.x & 7) + (blockIdx.x >> 3);   // XCD-local window grouping
  const int h = blockIdx.y, b = blockIdx.z;
  const int n0 = m * 2, n1 = n0 + 1;
  const int tid = threadIdx.x;
  const int wid = tid >> 6, lane = tid & 63;
  const int quad = lane >> 4, l16 = lane & 15;
  const int xg = wid >> 2;          // wave-group: 0 -> q-block n0, 1 -> n1
  const int wq4 = wid & 3;          // 16-row slice within the q-block
  const int nx = n0 + xg;

  __shared__ bf16_t Ks[2][64 * 64];
  __shared__ bf16_t Vs[2][64 * 64];
  __shared__ bf16_t Ps[8][16 * 72];

  const size_t hoff = (size_t)h * HD_;
  const size_t vtbase = (size_t)(b * H_ + h) * HD_ * S_;
  const size_t rowb = (size_t)(b * S_ + nx * 64);

  bf16x8 aq0, aq1;
  {
    const bf16_t* qr = q + (rowb + wq4 * 16 + l16) * D_ + hoff;
    aq0 = *(const bf16x8*)(qr + quad * 8);
    aq1 = *(const bf16x8*)(qr + 32 + quad * 8);
  }

  f32x4 o_acc[4];
  float lsum[4];
#pragma unroll
  for (int t = 0; t < 4; ++t) {
    o_acc[t] = (f32x4){0.f, 0.f, 0.f, 0.f};
    lsum[t] = 0.f;
  }

  const int srK = wid * 8 + (lane >> 3);
  const int scC = ((lane & 7) ^ ((lane >> 3) & 7)) * 8;
  const bf16_t* kbase = k + (size_t)(b * S_) * D_ + hoff;
  const bf16_t* vbase2 = vt + vtbase;
#define STAGE_KV(kb_, buf_) do { \
    GLOAD_LDS16(kbase + (size_t)((kb_) * 64 + srK) * D_ + scC, &Ks[buf_][wid * 512]); \
    GLOAD_LDS16(vbase2 + (size_t)srK * S_ + (kb_) * 64 + scC, &Vs[buf_][wid * 512]); \
  } while (0)

  const int ck0 = (quad ^ (l16 & 7)) * 8;
  const int ck1 = ((quad ^ 4) ^ (l16 & 7)) * 8;

  const int kb0 = (n0 >= W_ - 1) ? n0 - (W_ - 1) : 0;

  STAGE_KV(kb0, kb0 & 1);   // prologue

  for (int kb = kb0; kb <= n1; ++kb) {
    const int buf = kb & 1;
    if (kb < n1) { STAGE_KV(kb + 1, buf ^ 1); WAITV(2); }
    else        { WAITV(0); }
    BAR();

    // wave-uniform activity guard (xg fixed per wave)
    const bool active = (xg == 0) ? (kb <= n0) : (kb >= n1 - (W_ - 1));
    if (active) {
      f32x4 sacc[4];
#pragma unroll
      for (int t = 0; t < 4; ++t) sacc[t] = (f32x4){0.f, 0.f, 0.f, 0.f};
#pragma unroll
      for (int t = 0; t < 4; ++t) {
        const int rr = (t * 16 + l16) * 64;
        bf16x8 bk0 = *(const bf16x8*)&Ks[buf][rr + ck0];
        bf16x8 bk1 = *(const bf16x8*)&Ks[buf][rr + ck1];
        sacc[t] = __builtin_amdgcn_mfma_f32_16x16x32_bf16(aq0, bk0, sacc[t], 0, 0, 0);
        sacc[t] = __builtin_amdgcn_mfma_f32_16x16x32_bf16(aq1, bk1, sacc[t], 0, 0, 0);
      }

      const bool diag = (kb == nx);
#pragma unroll
      for (int r = 0; r < 4; ++r) {
        int qpos = wq4 * 16 + quad * 4 + r;
        union { bf16_t bv[4]; uint2 u; } pk;
        float rs = 0.f;
#pragma unroll
        for (int t = 0; t < 4; ++t) {
          float p = __builtin_exp2f(sacc[t][r]);
          if (diag && (t * 16 + l16 > qpos)) p = 0.f;
          rs += p;
          pk.bv[t] = (bf16_t)p;
        }
        lsum[r] += rs;
        *(uint2*)&Ps[wid][(quad * 4 + r) * 72 + l16 * 4] = pk.u;   // col' = pi(key)
      }

      bf16x8 pa0 = *(const bf16x8*)&Ps[wid][l16 * 72 + quad * 8];
      bf16x8 pa1 = *(const bf16x8*)&Ps[wid][l16 * 72 + 32 + quad * 8];
#pragma unroll
      for (int t = 0; t < 4; ++t) {
        const int rr = (t * 16 + l16) * 64;
        bf16x8 vb0 = *(const bf16x8*)&Vs[buf][rr + ck0];
        bf16x8 vb1 = *(const bf16x8*)&Vs[buf][rr + ck1];
        o_acc[t] = __builtin_amdgcn_mfma_f32_16x16x32_bf16(pa0, vb0, o_acc[t], 0, 0, 0);
        o_acc[t] = __builtin_amdgcn_mfma_f32_16x16x32_bf16(pa1, vb1, o_acc[t], 0, 0, 0);
      }
    }
    BAR();   // all waves done reading buf before next iter's stage overwrites buf^1
  }
#undef STAGE_KV

  float inv[4];
#pragma unroll
  for (int r = 0; r < 4; ++r) {
    float s = lsum[r];
#pragma unroll
    for (int off = 1; off < 16; off <<= 1) s += __shfl_xor(s, off);
    inv[r] = 1.f / s;
  }
#pragma unroll
  for (int t = 0; t < 4; ++t)
#pragma unroll
    for (int r = 0; r < 4; ++r) {
      int row = wq4 * 16 + quad * 4 + r;
      int col = t * 16 + l16;
      o[(rowb + row) * D_ + hoff + col] = (bf16_t)(o_acc[t][r] * inv[r]);
    }
}

// ---------------- launch ----------------
extern "C" void kernel_launch(void* const* d_in, const int* in_sizes, int n_in,
                              void* d_out, int out_size, void* d_ws, size_t ws_size,
                              hipStream_t stream) {
  const float* hs = (const float*)d_in[0];
  const int* pos  = (const int*)d_in[1];
  const float* wq = (const float*)d_in[2];
  const float* wk = (const float*)d_in[3];
  const float* wv = (const float*)d_in[4];
  const float* wo = (const float*)d_in[5];

  bf16_t* ws   = (bf16_t*)d_ws;
  bf16_t* hsb  = ws;                          // M_*D_
  bf16_t* wT   = hsb + (size_t)M_ * D_;       // 4*D_*D_  (wq|wk|wv|wo transposed)
  bf16_t* qkv  = wT + (size_t)4 * D_ * D_;    // 3*M_*D_ (q, k, vt slots)
  bf16_t* attn = qkv + (size_t)3 * M_ * D_;   // M_*D_
  bf16_t* qw  = qkv;
  bf16_t* kw  = qkv + (size_t)M_ * D_;
  bf16_t* vtg = qkv + (size_t)2 * M_ * D_;    // V transposed (written by gemm epilogue)

  prep_kernel<<<dim3((M_ * D_ / 4) / 256 + 4 * 1024), 256, 0, stream>>>(hs, hsb, wq, wk, wv, wo, wT);
  gemm_bk<24><<<dim3(1536), dim3(256), 0, stream>>>(hsb, wT, (void*)qkv, vtg, pos);
  attn_kernel<<<dim3(NB_ / 2, H_, B_), 512, 0, stream>>>(qw, kw, vtg, attn);
  gemm_bk<8><<<dim3(512), dim3(256), 0, stream>>>(attn, wT + (size_t)3 * D_ * D_, d_out, nullptr, pos);
}

// Round 14
// 210.111 us; speedup vs baseline: 1.0596x; 1.0596x over previous
//
#include <hip/hip_runtime.h>
#include <cstdint>
#include <cstddef>

#define B_ 2
#define S_ 4096
#define D_ 1024
#define H_ 16
#define HD_ 64
#define NB_ 64
#define W_ 8
#define M_ (B_*S_)   // 8192

// 0.125 (1/sqrt(HD)) * log2(e), folded into Q so attention softmax = exp2(S)
#define QSCALE 0.18033688011112042f
#define LOG2_10000_OVER_32 0.41524101186092034f

typedef __bf16 bf16_t;
typedef __bf16 bf16x8 __attribute__((ext_vector_type(8)));
typedef float f32x4 __attribute__((ext_vector_type(4)));

#define GLOAD_LDS16(gp, lp) \
  __builtin_amdgcn_global_load_lds((__attribute__((address_space(1))) void*)(gp), \
                                   (__attribute__((address_space(3))) void*)(lp), 16, 0, 0)
#define WAITV(n) asm volatile("s_waitcnt vmcnt(" #n ")" ::: "memory")
#define BAR() do { __builtin_amdgcn_s_barrier(); asm volatile("" ::: "memory"); } while (0)

// ---------------- fused prep: fp32->bf16 cast of hidden states + weight transpose ------
__global__ __launch_bounds__(256) void prep_kernel(const float* __restrict__ hs,
                                                   bf16_t* __restrict__ hsb,
                                                   const float* __restrict__ w0,
                                                   const float* __restrict__ w1,
                                                   const float* __restrict__ w2,
                                                   const float* __restrict__ w3,
                                                   bf16_t* __restrict__ wT) {
  __shared__ float tile[32][33];
  const int bid = blockIdx.x;
  if (bid < (M_ * D_ / 4) / 256) {
    int i = bid * 256 + threadIdx.x;
    float4 v = ((const float4*)hs)[i];
    union { bf16_t b[4]; uint2 u; } cv;
    cv.b[0] = (bf16_t)v.x; cv.b[1] = (bf16_t)v.y; cv.b[2] = (bf16_t)v.z; cv.b[3] = (bf16_t)v.w;
    ((uint2*)hsb)[i] = cv.u;
  } else {
    const int b2 = bid - (M_ * D_ / 4) / 256;
    const int z = b2 >> 10;                 // 1024 tiles per matrix (32x32 grid)
    const int rem = b2 & 1023;
    const int bx = rem & 31, by = rem >> 5;
    const float* w = (z == 0) ? w0 : (z == 1) ? w1 : (z == 2) ? w2 : w3;
    bf16_t* wt = wT + (size_t)z * D_ * D_;
    const int tx = threadIdx.x & 31, ty = threadIdx.x >> 5;
    const int x = bx * 32 + tx;
    const int y0 = by * 32;
    for (int i = ty; i < 32; i += 8)
      tile[i][tx] = w[(size_t)(y0 + i) * D_ + x];
    __syncthreads();
    const int x2 = by * 32 + tx;   // k
    const int y2 = bx * 32;        // n base
    for (int i = ty; i < 32; i += 8)
      wt[(size_t)(y2 + i) * D_ + x2] = (bf16_t)tile[tx][i];
  }
}

// ---------------- GEMM: 128xBN tile, BK=32, 3-buffer counted-vmcnt pipeline ------------
// R12 config (proven best, 210.2 us total): PWN=64 QKV (768 blocks, 2 blocks/CU),
// PWN=32 proj (512 blocks, 2 blocks/CU), depth-2 counted vmcnt, VGPR 64.
// A/B ledger (closed): depth-1@3-blocks worse (R8); 1-block lockstep worse (R2-R6);
// acc[8][4] reg-cap spill (R5); 128x128 4-wave 3-block worse — VGPR 100, FETCH +68%,
// occ 18% (R13). Counted depth-2 at 2 blocks/CU with 256-wide BN is the optimum.
// R14: QKV within-XCD order retiled (nb-quarter, mb, nb%3): L2 working set per
// quarter = 3 B panels (1.5 MB) + 8 A panels (2 MB) = 3.5 MB < 4 MB, so A stays
// L2-resident across quarters (FETCH evidence: 75 MB vs ~22 MB unique input).
template<int NBC, int PWN>
__global__ __launch_bounds__(512, 4) void gemm_bk(const bf16_t* __restrict__ A,
                                                  const bf16_t* __restrict__ Bt,
                                                  void* __restrict__ Cbase,
                                                  bf16_t* __restrict__ vt_out,
                                                  const int* __restrict__ pos_ids) {
  constexpr int BN = PWN * 4;
  constexpr int NR = PWN / 32;            // B gloads per wave per stage
  constexpr int BUFEL = 4096 + PWN * 128; // elements per buffer (A 128x32 | B BNx32)
  const int bid = blockIdx.x;
  int mb, nb;
  if constexpr (NBC == 12) {
    // XCD-local L2 tiling: xcd = bid&7 owns mb in [8x,8x+8); within, iterate
    // (nbq, mbl, nbl) so each nb-quarter's 3 B panels + 8 A panels co-reside in L2.
    const int xcd = bid & 7, r = bid >> 3;      // r in [0,96)
    const int nbq = r / 24, rem = r % 24;
    mb = xcd * 8 + rem / 3;
    nb = nbq * 3 + rem % 3;
  } else {
    const int sid = (bid & 7) * (NBC * 8) + (bid >> 3);  // nwg%8==0, bijective
    mb = sid / NBC; nb = sid % NBC;
  }
  const int mbase = mb * 128, nbase = nb * BN;
  const int tid = threadIdx.x;
  const int wid = tid >> 6, lane = tid & 63;
  const int quad = lane >> 4, l16 = lane & 15;
  const int wr = wid >> 2, wc = wid & 3;               // 2 x 4 wave grid; per-wave 64 x PWN

  __shared__ bf16_t lds[3 * BUFEL];

  // staging rows: wave wid stages A rows [wid*16,+16) (1 gload) and B rows
  // [wid*16,+16) (+ [wid*16+128,+16) if NR==2). Linear LDS dest.
  // Source chunk pre-swizzled: schunk = (lane&3) ^ ((row>>1)&3) = (lane&3)^((lane>>3)&3).
  const int srow = wid * 16 + (lane >> 2);
  const int schunk = (lane & 3) ^ ((lane >> 3) & 3);
  const bf16_t* gAb = A  + (size_t)(mbase + srow) * D_ + schunk * 8;
  const bf16_t* gBb = Bt + (size_t)(nbase + srow) * D_ + schunk * 8;
  // read-side swizzled chunk offset (elements): chunk = quad ^ ((l16>>1)&3)
  const int quadx = (quad ^ ((l16 >> 1) & 3)) * 8;

  // buf layout (elements): [0,4096) = A (128x32), [4096,BUFEL) = B (BNx32)
#define STAGE(kt) do { \
    bf16_t* pa_ = lds + ((kt) % 3) * BUFEL + wid * 512; \
    bf16_t* pb_ = lds + ((kt) % 3) * BUFEL + 4096 + wid * 512; \
    GLOAD_LDS16(gAb + (kt) * 32, pa_); \
    GLOAD_LDS16(gBb + (kt) * 32, pb_); \
    if constexpr (NR == 2) \
      GLOAD_LDS16(gBb + (size_t)128 * D_ + (kt) * 32, pb_ + 4096); } while (0)

  // steady-state counted wait: completes S(kt+1), leaves S(kt+2)'s loads in flight.
#define WTS() do { if constexpr (NR == 2) WAITV(3); else WAITV(2); } while (0)

  f32x4 acc[4][PWN / 16];
#pragma unroll
  for (int m = 0; m < 4; ++m)
#pragma unroll
    for (int n = 0; n < PWN / 16; ++n) acc[m][n] = (f32x4){0.f, 0.f, 0.f, 0.f};

  // Phase(kt): {ds_reads | issue stage | MFMAs prio1 | wait | BAR}.
#define PHASE(kt, STG, WT) do { \
    const bf16_t* Ab_ = lds + ((kt) % 3) * BUFEL; \
    const bf16_t* Bb_ = Ab_ + 4096; \
    bf16x8 af_[4], bf_[PWN / 16]; \
    _Pragma("unroll") \
    for (int m = 0; m < 4; ++m) \
      af_[m] = *(const bf16x8*)&Ab_[(wr * 64 + m * 16 + l16) * 32 + quadx]; \
    _Pragma("unroll") \
    for (int n = 0; n < PWN / 16; ++n) \
      bf_[n] = *(const bf16x8*)&Bb_[(wc * PWN + n * 16 + l16) * 32 + quadx]; \
    STG; \
    __builtin_amdgcn_s_setprio(1); \
    _Pragma("unroll") \
    for (int m = 0; m < 4; ++m) \
      _Pragma("unroll") \
      for (int n = 0; n < PWN / 16; ++n) \
        acc[m][n] = __builtin_amdgcn_mfma_f32_16x16x32_bf16(af_[m], bf_[n], acc[m][n], 0, 0, 0); \
    __builtin_amdgcn_s_setprio(0); \
    WT; \
    BAR(); \
  } while (0)

  // depth-2 counted pipeline (proven R4/R7): WTS() completes S(kt+1).
  STAGE(0); STAGE(1);
  WTS();
  BAR();
#pragma unroll 3
  for (int kt = 0; kt < 30; ++kt)
    PHASE(kt, STAGE(kt + 2), WTS());
  PHASE(30, (void)0, WAITV(0));   // drains S(31)
  PHASE(31, (void)0, (void)0);

  // ---------------- epilogue ----------------
  // C/D fragment map: row = mbase + wr*64 + m*16 + quad*4 + r, col = nbase + wc*PWN + n*16 + l16.
  if constexpr (NBC == 12) {
    const int zsl = nb >> 2;           // 0=Q, 1=K, 2=V
    if (zsl < 2) {
      bf16_t* Cp = (bf16_t*)Cbase + (size_t)zsl * M_ * D_;
      const float qsc = (zsl == 0) ? QSCALE : 1.0f;
      float invf[2];
#pragma unroll
      for (int ni = 0; ni < 2; ++ni)
        invf[ni] = __builtin_exp2f(-(float)(ni * 16 + l16) * LOG2_10000_OVER_32);
      const int colb = (nb & 3) * 256 + wc * 64;   // within-slice col base; wave = one head
#pragma unroll
      for (int m = 0; m < 4; ++m) {
#pragma unroll
        for (int r = 0; r < 4; ++r) {
          int row = mbase + wr * 64 + m * 16 + quad * 4 + r;
          float fpos = (float)pos_ids[row];
#pragma unroll
          for (int ni = 0; ni < 2; ++ni) {
            float sn, cs;
            __sincosf(fpos * invf[ni], &sn, &cs);
            float x1 = acc[m][ni][r], x2 = acc[m][ni + 2][r];
            int col = colb + ni * 16 + l16;
            Cp[(size_t)row * D_ + col]      = (bf16_t)((x1 * cs - x2 * sn) * qsc);
            Cp[(size_t)row * D_ + col + 32] = (bf16_t)((x2 * cs + x1 * sn) * qsc);
          }
        }
      }
    } else {
      // V: transposed + pi-permuted, pi(j) = (j%16)*4 + j/16 within each 64-row seq block.
      const int h = (nb & 3) * 4 + wc;
      const int g = mb * 2 + wr;              // global 64-row block in M
      const int bb = g >> 6, sblk = g & 63;   // batch, seq-block
      size_t vbase = (size_t)(bb * H_ + h) * HD_ * S_;
#pragma unroll
      for (int n = 0; n < 4; ++n) {
        int d = n * 16 + l16;
        union { bf16_t bv[16]; uint4 u[2]; } pk;
#pragma unroll
        for (int r = 0; r < 4; ++r)
#pragma unroll
          for (int mi = 0; mi < 4; ++mi)
            pk.bv[r * 4 + mi] = (bf16_t)acc[mi][n][r];
        size_t addr = vbase + (size_t)d * S_ + (size_t)sblk * 64 + quad * 16;
        *(uint4*)&vt_out[addr]     = pk.u[0];
        *(uint4*)&vt_out[addr + 8] = pk.u[1];
      }
    }
  } else {
    // plain fp32 output (out projection)
    float* Cp = (float*)Cbase;
#pragma unroll
    for (int m = 0; m < 4; ++m)
#pragma unroll
      for (int n = 0; n < PWN / 16; ++n)
#pragma unroll
        for (int r = 0; r < 4; ++r) {
          int row = mbase + wr * 64 + m * 16 + quad * 4 + r;
          int col = nbase + wc * PWN + n * 16 + l16;
          Cp[(size_t)row * D_ + col] = acc[m][n][r];
        }
  }
#undef PHASE
#undef STAGE
#undef WTS
}

// ---------------- block-sparse flash attention: 2 q-blocks, 8 waves ----------------
// R10 structure + R12 XCD-local m-swizzle (both proven): waves 0-3 own q-block n0,
// waves 4-7 own n1; K/V staged once, counted WAITV(2) pipeline; XOR chunk swizzle
// both-sides (conflict-free); m = 4*(x&7)+(x>>3) keeps overlapping K/V windows on
// one XCD's L2. LDS 50.4 KB -> 3 blocks/CU.
__global__ __launch_bounds__(512) void attn_kernel(const bf16_t* __restrict__ q,
                                                   const bf16_t* __restrict__ k,
                                                   const bf16_t* __restrict__ vt,
                                                   bf16_t* __restrict__ o) {
  const int m = 4 * (blockIdx.x & 7) + (blockIdx.x >> 3);   // XCD-local window grouping
  const int h = blockIdx.y, b = blockIdx.z;
  const int n0 = m * 2, n1 = n0 + 1;
  const int tid = threadIdx.x;
  const int wid = tid >> 6, lane = tid & 63;
  const int quad = lane >> 4, l16 = lane & 15;
  const int xg = wid >> 2;          // wave-group: 0 -> q-block n0, 1 -> n1
  const int wq4 = wid & 3;          // 16-row slice within the q-block
  const int nx = n0 + xg;

  __shared__ bf16_t Ks[2][64 * 64];
  __shared__ bf16_t Vs[2][64 * 64];
  __shared__ bf16_t Ps[8][16 * 72];

  const size_t hoff = (size_t)h * HD_;
  const size_t vtbase = (size_t)(b * H_ + h) * HD_ * S_;
  const size_t rowb = (size_t)(b * S_ + nx * 64);

  bf16x8 aq0, aq1;
  {
    const bf16_t* qr = q + (rowb + wq4 * 16 + l16) * D_ + hoff;
    aq0 = *(const bf16x8*)(qr + quad * 8);
    aq1 = *(const bf16x8*)(qr + 32 + quad * 8);
  }

  f32x4 o_acc[4];
  float lsum[4];
#pragma unroll
  for (int t = 0; t < 4; ++t) {
    o_acc[t] = (f32x4){0.f, 0.f, 0.f, 0.f};
    lsum[t] = 0.f;
  }

  const int srK = wid * 8 + (lane >> 3);
  const int scC = ((lane & 7) ^ ((lane >> 3) & 7)) * 8;
  const bf16_t* kbase = k + (size_t)(b * S_) * D_ + hoff;
  const bf16_t* vbase2 = vt + vtbase;
#define STAGE_KV(kb_, buf_) do { \
    GLOAD_LDS16(kbase + (size_t)((kb_) * 64 + srK) * D_ + scC, &Ks[buf_][wid * 512]); \
    GLOAD_LDS16(vbase2 + (size_t)srK * S_ + (kb_) * 64 + scC, &Vs[buf_][wid * 512]); \
  } while (0)

  const int ck0 = (quad ^ (l16 & 7)) * 8;
  const int ck1 = ((quad ^ 4) ^ (l16 & 7)) * 8;

  const int kb0 = (n0 >= W_ - 1) ? n0 - (W_ - 1) : 0;

  STAGE_KV(kb0, kb0 & 1);   // prologue

  for (int kb = kb0; kb <= n1; ++kb) {
    const int buf = kb & 1;
    if (kb < n1) { STAGE_KV(kb + 1, buf ^ 1); WAITV(2); }
    else        { WAITV(0); }
    BAR();

    // wave-uniform activity guard (xg fixed per wave)
    const bool active = (xg == 0) ? (kb <= n0) : (kb >= n1 - (W_ - 1));
    if (active) {
      f32x4 sacc[4];
#pragma unroll
      for (int t = 0; t < 4; ++t) sacc[t] = (f32x4){0.f, 0.f, 0.f, 0.f};
#pragma unroll
      for (int t = 0; t < 4; ++t) {
        const int rr = (t * 16 + l16) * 64;
        bf16x8 bk0 = *(const bf16x8*)&Ks[buf][rr + ck0];
        bf16x8 bk1 = *(const bf16x8*)&Ks[buf][rr + ck1];
        sacc[t] = __builtin_amdgcn_mfma_f32_16x16x32_bf16(aq0, bk0, sacc[t], 0, 0, 0);
        sacc[t] = __builtin_amdgcn_mfma_f32_16x16x32_bf16(aq1, bk1, sacc[t], 0, 0, 0);
      }

      const bool diag = (kb == nx);
#pragma unroll
      for (int r = 0; r < 4; ++r) {
        int qpos = wq4 * 16 + quad * 4 + r;
        union { bf16_t bv[4]; uint2 u; } pk;
        float rs = 0.f;
#pragma unroll
        for (int t = 0; t < 4; ++t) {
          float p = __builtin_exp2f(sacc[t][r]);
          if (diag && (t * 16 + l16 > qpos)) p = 0.f;
          rs += p;
          pk.bv[t] = (bf16_t)p;
        }
        lsum[r] += rs;
        *(uint2*)&Ps[wid][(quad * 4 + r) * 72 + l16 * 4] = pk.u;   // col' = pi(key)
      }

      bf16x8 pa0 = *(const bf16x8*)&Ps[wid][l16 * 72 + quad * 8];
      bf16x8 pa1 = *(const bf16x8*)&Ps[wid][l16 * 72 + 32 + quad * 8];
#pragma unroll
      for (int t = 0; t < 4; ++t) {
        const int rr = (t * 16 + l16) * 64;
        bf16x8 vb0 = *(const bf16x8*)&Vs[buf][rr + ck0];
        bf16x8 vb1 = *(const bf16x8*)&Vs[buf][rr + ck1];
        o_acc[t] = __builtin_amdgcn_mfma_f32_16x16x32_bf16(pa0, vb0, o_acc[t], 0, 0, 0);
        o_acc[t] = __builtin_amdgcn_mfma_f32_16x16x32_bf16(pa1, vb1, o_acc[t], 0, 0, 0);
      }
    }
    BAR();   // all waves done reading buf before next iter's stage overwrites buf^1
  }
#undef STAGE_KV

  float inv[4];
#pragma unroll
  for (int r = 0; r < 4; ++r) {
    float s = lsum[r];
#pragma unroll
    for (int off = 1; off < 16; off <<= 1) s += __shfl_xor(s, off);
    inv[r] = 1.f / s;
  }
#pragma unroll
  for (int t = 0; t < 4; ++t)
#pragma unroll
    for (int r = 0; r < 4; ++r) {
      int row = wq4 * 16 + quad * 4 + r;
      int col = t * 16 + l16;
      o[(rowb + row) * D_ + hoff + col] = (bf16_t)(o_acc[t][r] * inv[r]);
    }
}

// ---------------- launch ----------------
extern "C" void kernel_launch(void* const* d_in, const int* in_sizes, int n_in,
                              void* d_out, int out_size, void* d_ws, size_t ws_size,
                              hipStream_t stream) {
  const float* hs = (const float*)d_in[0];
  const int* pos  = (const int*)d_in[1];
  const float* wq = (const float*)d_in[2];
  const float* wk = (const float*)d_in[3];
  const float* wv = (const float*)d_in[4];
  const float* wo = (const float*)d_in[5];

  bf16_t* ws   = (bf16_t*)d_ws;
  bf16_t* hsb  = ws;                          // M_*D_
  bf16_t* wT   = hsb + (size_t)M_ * D_;       // 4*D_*D_  (wq|wk|wv|wo transposed)
  bf16_t* qkv  = wT + (size_t)4 * D_ * D_;    // 3*M_*D_ (q, k, vt slots)
  bf16_t* attn = qkv + (size_t)3 * M_ * D_;   // M_*D_
  bf16_t* qw  = qkv;
  bf16_t* kw  = qkv + (size_t)M_ * D_;
  bf16_t* vtg = qkv + (size_t)2 * M_ * D_;    // V transposed (written by gemm epilogue)

  prep_kernel<<<dim3((M_ * D_ / 4) / 256 + 4 * 1024), 256, 0, stream>>>(hs, hsb, wq, wk, wv, wo, wT);
  gemm_bk<12, 64><<<dim3(768), dim3(512), 0, stream>>>(hsb, wT, (void*)qkv, vtg, pos);
  attn_kernel<<<dim3(NB_ / 2, H_, B_), 512, 0, stream>>>(qw, kw, vtg, attn);
  gemm_bk<8, 32><<<dim3(512), dim3(512), 0, stream>>>(attn, wT + (size_t)3 * D_ * D_, d_out, nullptr, pos);
}